// Round 1
// baseline (694.189 us; speedup 1.0000x reference)
//
#include <hip/hip_runtime.h>
#include <cfloat>
#include <cmath>

#define NROWS 32768
#define DIM   256
#define KC    1024

// ---------------- wnorm: ||w_k||^2 in fp64 (and fp32 copy) ----------------
__global__ __launch_bounds__(256) void wnorm_kernel(const float* __restrict__ w,
                                                    double* __restrict__ wnorm64,
                                                    float* __restrict__ wnormf) {
    int k = blockIdx.x * 256 + threadIdx.x;
    double acc = 0.0;
#pragma unroll 8
    for (int d = 0; d < DIM; ++d) {
        float wv = w[(size_t)d * KC + k];
        acc += (double)wv * (double)wv;
    }
    wnorm64[k] = acc;
    wnormf[k] = (float)acc;
}

// ---------------- main fused kernel ----------------
// 16 rows/block, 256 threads. Thread (tc,tr): tc=t&63 owns cols [tc*16,tc*16+16),
// tr=t>>6 owns rows [tr*4, tr*4+4). fp32 screen, fp64 refine of near-ties.
__global__ __launch_bounds__(256) void vq_main(const float* __restrict__ x,
                                               const float* __restrict__ w,
                                               const double* __restrict__ wnorm64,
                                               const float* __restrict__ wnormf,
                                               float* __restrict__ out_q,
                                               float* __restrict__ out_idx,
                                               int* __restrict__ ws_idx,
                                               int* __restrict__ counts,
                                               double* __restrict__ loss_sum) {
    __shared__ float  xs[16][DIM];       // 16 KB
    __shared__ float  redv[16][64];      // 4 KB
    __shared__ int    redi[16][64];      // 4 KB
    __shared__ double redv64[16][64];    // 8 KB
    __shared__ float  rowmin[16];
    __shared__ int    rowk[16];
    __shared__ double wsum[4];

    const int t = threadIdx.x;
    const int row0 = blockIdx.x * 16;

    // stage x tile (16 x 256 fp32), coalesced float4
    {
        const float4* s4 = reinterpret_cast<const float4*>(x + (size_t)row0 * DIM) + t * 4;
        float4* d4 = reinterpret_cast<float4*>(&xs[0][0]) + t * 4;
        d4[0] = s4[0]; d4[1] = s4[1]; d4[2] = s4[2]; d4[3] = s4[3];
    }
    __syncthreads();

    const int tc = t & 63;
    const int tr = t >> 6;
    const int tr4 = tr * 4;
    const int kbase = tc * 16;

    float acc[4][16];
#pragma unroll
    for (int i = 0; i < 4; ++i)
#pragma unroll
        for (int j = 0; j < 16; ++j) acc[i][j] = 0.f;

    // dot(x_row, w_col) for 4 rows x 16 cols; w read through L1/L2 (w = 1MB, L2-resident)
#pragma unroll 2
    for (int d = 0; d < DIM; ++d) {
        const float4* wr = reinterpret_cast<const float4*>(w + (size_t)d * KC + kbase);
        float4 w0 = wr[0], w1 = wr[1], w2 = wr[2], w3 = wr[3];
        float wv[16] = {w0.x,w0.y,w0.z,w0.w, w1.x,w1.y,w1.z,w1.w,
                        w2.x,w2.y,w2.z,w2.w, w3.x,w3.y,w3.z,w3.w};
        float xv[4];
#pragma unroll
        for (int i = 0; i < 4; ++i) xv[i] = xs[tr4 + i][d];
#pragma unroll
        for (int i = 0; i < 4; ++i)
#pragma unroll
            for (int j = 0; j < 16; ++j)
                acc[i][j] = fmaf(xv[i], wv[j], acc[i][j]);
    }

    float wn[16];
#pragma unroll
    for (int j = 0; j < 16; ++j) wn[j] = wnormf[kbase + j];

    // fp32 per-thread min (score = ||w||^2 - 2 x.w ; ||x||^2 constant per row)
    float minv[4];
#pragma unroll
    for (int i = 0; i < 4; ++i) minv[i] = FLT_MAX;
#pragma unroll
    for (int j = 0; j < 16; ++j)
#pragma unroll
        for (int i = 0; i < 4; ++i) {
            float s = wn[j] - 2.f * acc[i][j];
            if (s < minv[i]) minv[i] = s;
        }

#pragma unroll
    for (int i = 0; i < 4; ++i) redv[tr4 + i][tc] = minv[i];
    __syncthreads();
    if (t < 16) {
        float v = redv[t][0];
        for (int c = 1; c < 64; ++c) { float cv = redv[t][c]; if (cv < v) v = cv; }
        rowmin[t] = v;
    }
    __syncthreads();

    // fp64 refinement of all candidates within margin of the fp32 min
    const float margin = 1e-3f;
    double bestv[4]; int bestk[4];
#pragma unroll
    for (int i = 0; i < 4; ++i) { bestv[i] = 1e300; bestk[i] = 0x7fffffff; }
    for (int i = 0; i < 4; ++i) {
        const int r = tr4 + i;
        const float thr = rowmin[r] + margin;
        for (int j = 0; j < 16; ++j) {
            float s = wn[j] - 2.f * acc[i][j];
            if (s <= thr) {
                const int k = kbase + j;
                const float* wk = w + k;
                double dot = 0.0;
#pragma unroll 8
                for (int d = 0; d < DIM; ++d)
                    dot += (double)xs[r][d] * (double)wk[(size_t)d * KC];
                double s64 = wnorm64[k] - 2.0 * dot;
                if (s64 < bestv[i] || (s64 == bestv[i] && k < bestk[i])) {
                    bestv[i] = s64; bestk[i] = k;
                }
            }
        }
    }
#pragma unroll
    for (int i = 0; i < 4; ++i) { redv64[tr4 + i][tc] = bestv[i]; redi[tr4 + i][tc] = bestk[i]; }
    __syncthreads();
    if (t < 16) {
        double v = redv64[t][0]; int bi = redi[t][0];
        for (int c = 1; c < 64; ++c) {
            double cv = redv64[t][c]; int ci = redi[t][c];
            if (cv < v || (cv == v && ci < bi)) { v = cv; bi = ci; }
        }
        rowk[t] = bi;
        const int gr = row0 + t;
        out_idx[gr] = (float)bi;          // indices output stored as float
        ws_idx[gr] = bi;
        atomicAdd(&counts[bi], 1);        // histogram for perplexity
    }
    __syncthreads();

    // quantized_skip + loss partials: 16 threads per row, 16 elems per thread
    {
        const int r = t >> 4;
        const int dbase = (t & 15) * 16;
        const int k = rowk[r];
        const int gr = row0 + r;
        double lsum = 0.0;
#pragma unroll
        for (int c = 0; c < 16; ++c) {
            const int d = dbase + c;
            float q = w[(size_t)d * KC + k];
            float xv = xs[r][d];
            out_q[(size_t)gr * DIM + d] = xv + (q - xv);   // replicate reference fp32 arithmetic
            double diff = (double)q - (double)xv;
            lsum += diff * diff;
        }
        for (int off = 32; off > 0; off >>= 1) lsum += __shfl_down(lsum, off);
        if ((t & 63) == 0) wsum[t >> 6] = lsum;
    }
    __syncthreads();
    if (t == 0) atomicAdd(loss_sum, wsum[0] + wsum[1] + wsum[2] + wsum[3]);
}

// ---------------- scatter the one-hot ones ----------------
__global__ __launch_bounds__(256) void scatter_kernel(const int* __restrict__ idx,
                                                      float* __restrict__ enc) {
    const int n = blockIdx.x * 256 + threadIdx.x;
    enc[(size_t)n * KC + idx[n]] = 1.0f;
}

// ---------------- finalize loss + perplexity ----------------
__global__ __launch_bounds__(1024) void final_kernel(const int* __restrict__ counts,
                                                     const double* __restrict__ loss_sum,
                                                     float* __restrict__ out_loss,
                                                     float* __restrict__ out_ppl) {
    const int t = threadIdx.x;
    double p = (double)counts[t] * (1.0 / 32768.0);
    double term = -p * log(p + 1e-10);
    for (int off = 32; off > 0; off >>= 1) term += __shfl_down(term, off);
    __shared__ double ws[16];
    if ((t & 63) == 0) ws[t >> 6] = term;
    __syncthreads();
    if (t == 0) {
        double s = 0.0;
        for (int i = 0; i < 16; ++i) s += ws[i];
        *out_ppl = (float)exp(s);
        *out_loss = (float)(1.25 * loss_sum[0] * (1.0 / 8388608.0));
    }
}

extern "C" void kernel_launch(void* const* d_in, const int* in_sizes, int n_in,
                              void* d_out, int out_size, void* d_ws, size_t ws_size,
                              hipStream_t stream) {
    const float* x = (const float*)d_in[0];   // [32,32,32,256] fp32
    const float* w = (const float*)d_in[1];   // [256,1024] fp32

    float* out = (float*)d_out;
    float* out_q    = out;                        // 8388608
    float* out_loss = out + 8388608;              // 1
    float* out_ppl  = out + 8388609;              // 1
    float* out_enc  = out + 8388610;              // 33554432
    float* out_idx  = out + 8388610 + 33554432;   // 32768

    // ws layout: [0,8) double loss_sum | [8,4104) int counts[1024]
    //            [4104,12296) double wnorm64[1024] | [12296,16392) float wnormf[1024]
    //            [16392,...) int idx[32768]
    char* wsb = (char*)d_ws;
    double* loss_sum = (double*)wsb;
    int*    counts   = (int*)(wsb + 8);
    double* wnorm64  = (double*)(wsb + 4104);
    float*  wnormf   = (float*)(wsb + 12296);
    int*    ws_idx   = (int*)(wsb + 16392);

    hipMemsetAsync(d_ws, 0, 4104, stream);                              // loss_sum + counts
    hipMemsetAsync(out_enc, 0, (size_t)33554432 * sizeof(float), stream); // one-hot zeros

    wnorm_kernel<<<KC / 256, 256, 0, stream>>>(w, wnorm64, wnormf);
    vq_main<<<NROWS / 16, 256, 0, stream>>>(x, w, wnorm64, wnormf,
                                            out_q, out_idx, ws_idx, counts, loss_sum);
    scatter_kernel<<<NROWS / 256, 256, 0, stream>>>(ws_idx, out_enc);
    final_kernel<<<1, 1024, 0, stream>>>(counts, loss_sum, out_loss, out_ppl);
}

// Round 2
// 183.731 us; speedup vs baseline: 3.7783x; 3.7783x over previous
//
#include <hip/hip_runtime.h>
#include <cfloat>
#include <cmath>
#include <stdint.h>

#define NROWS 32768
#define DIM   256
#define KC    1024

typedef short bf16x8 __attribute__((ext_vector_type(8)));
typedef float f32x4  __attribute__((ext_vector_type(4)));

__device__ inline unsigned short f2bf(float f) {
    unsigned u = __float_as_uint(f);
    u = (u + 0x7fffu + ((u >> 16) & 1u)) >> 16;   // RNE
    return (unsigned short)u;
}
__device__ inline float bf2f(unsigned short h) {
    return __uint_as_float(((unsigned)h) << 16);
}

// ---------- prep_w: pack w into MFMA B-frag layout (hi/lo bf16) + transpose ----------
// unit t = ct*512 + ks*64 + l ; element j (0..7): w[(ks*32 + (l>>4)*8 + j)][ct*16 + (l&15)]
__global__ __launch_bounds__(256) void prep_w(const float* __restrict__ w,
                                              uint4* __restrict__ wph,
                                              uint4* __restrict__ wpl,
                                              float* __restrict__ wT) {
    const int t = blockIdx.x * 256 + threadIdx.x;
    const int l = t & 63;
    const int ks = (t >> 6) & 7;
    const int ct = t >> 9;
    const int c = ct * 16 + (l & 15);
    const int kbase = ks * 32 + ((l >> 4) << 3);
    union { unsigned short u[8]; uint4 v; } H, L;
#pragma unroll
    for (int j = 0; j < 8; ++j) {
        float v = w[(size_t)(kbase + j) * KC + c];
        unsigned short hh = f2bf(v);
        H.u[j] = hh;
        L.u[j] = f2bf(v - bf2f(hh));
        wT[(size_t)c * DIM + kbase + j] = v;
    }
    wph[t] = H.v;
    wpl[t] = L.v;
}

// ---------- wnorm from wT (fp64 + fp32 copy) ----------
__global__ __launch_bounds__(256) void wnorm_kernel(const float* __restrict__ wT,
                                                    double* __restrict__ wnorm64,
                                                    float* __restrict__ wnormf) {
    const int k = blockIdx.x * 256 + threadIdx.x;
    const float* p = wT + (size_t)k * DIM;
    double acc = 0.0;
#pragma unroll 8
    for (int d = 0; d < DIM; ++d) acc += (double)p[d] * (double)p[d];
    wnorm64[k] = acc;
    wnormf[k] = (float)acc;
}

// ---------- main fused kernel ----------
__global__ __launch_bounds__(256, 2) void vq_mfma(
    const float* __restrict__ x,
    const char* __restrict__ wph, const char* __restrict__ wpl,
    const float* __restrict__ wT,
    const double* __restrict__ wnorm64, const float* __restrict__ wnormf,
    float* __restrict__ out_q, float* __restrict__ out_idx, float* __restrict__ out_enc,
    int* __restrict__ counts, double* __restrict__ loss_sum)
{
    __shared__ char ldsbuf[65536];    // hi [0,32K), lo [32K,64K)
    __shared__ int rowk[64];
    __shared__ double wsum[4];

    const int t = threadIdx.x;
    const int l = t & 63;
    const int wv = t >> 6;
    const int blockRow0 = blockIdx.x * 64;
    const int r0 = blockRow0 + wv * 16;

    // ---- A fragments: 16 rows x 256 k, hi/lo bf16, converted in-register ----
    bf16x8 ah[8], al[8];
    {
        const float* xb = x + (size_t)(r0 + (l & 15)) * DIM + ((l >> 4) << 3);
#pragma unroll
        for (int ks = 0; ks < 8; ++ks) {
            float4 p0 = *(const float4*)(xb + ks * 32);
            float4 p1 = *(const float4*)(xb + ks * 32 + 4);
            float f[8] = {p0.x, p0.y, p0.z, p0.w, p1.x, p1.y, p1.z, p1.w};
            union { unsigned short u[8]; bf16x8 v; } H, L;
#pragma unroll
            for (int j = 0; j < 8; ++j) {
                unsigned short hh = f2bf(f[j]);
                H.u[j] = hh;
                L.u[j] = f2bf(f[j] - bf2f(hh));
            }
            ah[ks] = H.v; al[ks] = L.v;
        }
    }

    // top-3 per row (4 rows per lane, cols == l&15 mod 16)
    float tv0[4], tv1[4], tv2[4];
    int   tk0[4], tk1[4], tk2[4];
#pragma unroll
    for (int r = 0; r < 4; ++r) { tv0[r] = tv1[r] = tv2[r] = FLT_MAX; tk0[r] = tk1[r] = tk2[r] = 0; }

    for (int cg = 0; cg < 16; ++cg) {
        __syncthreads();   // prev readers done before overwrite
        {
            const char* gh = wph + (size_t)cg * 32768 + wv * 1024 + l * 16;
            const char* gl = wpl + (size_t)cg * 32768 + wv * 1024 + l * 16;
            char* lp = ldsbuf + wv * 1024;
#pragma unroll
            for (int i = 0; i < 8; ++i) {
                __builtin_amdgcn_global_load_lds(
                    (const __attribute__((address_space(1))) void*)(gh + i * 4096),
                    (__attribute__((address_space(3))) void*)(lp + i * 4096), 16, 0, 0);
                __builtin_amdgcn_global_load_lds(
                    (const __attribute__((address_space(1))) void*)(gl + i * 4096),
                    (__attribute__((address_space(3))) void*)(lp + 32768 + i * 4096), 16, 0, 0);
            }
        }
        __syncthreads();   // drains vmcnt before barrier (compiler-inserted)

        f32x4 acc[4];
#pragma unroll
        for (int ct = 0; ct < 4; ++ct) acc[ct] = (f32x4){0.f, 0.f, 0.f, 0.f};

#pragma unroll
        for (int ks = 0; ks < 8; ++ks) {
#pragma unroll
            for (int ct = 0; ct < 4; ++ct) {
                bf16x8 bh = *(const bf16x8*)(ldsbuf + ((ct * 8 + ks) * 64 + l) * 16);
                bf16x8 bl = *(const bf16x8*)(ldsbuf + 32768 + ((ct * 8 + ks) * 64 + l) * 16);
                acc[ct] = __builtin_amdgcn_mfma_f32_16x16x32_bf16(ah[ks], bh, acc[ct], 0, 0, 0);
                acc[ct] = __builtin_amdgcn_mfma_f32_16x16x32_bf16(al[ks], bh, acc[ct], 0, 0, 0);
                acc[ct] = __builtin_amdgcn_mfma_f32_16x16x32_bf16(ah[ks], bl, acc[ct], 0, 0, 0);
            }
        }

#pragma unroll
        for (int ct = 0; ct < 4; ++ct) {
            const int k = (cg * 4 + ct) * 16 + (l & 15);
            const float wn = wnormf[k];
#pragma unroll
            for (int r = 0; r < 4; ++r) {
                float s = wn - 2.0f * acc[ct][r];
                if (s < tv2[r]) {
                    if (s < tv1[r]) {
                        tv2[r] = tv1[r]; tk2[r] = tk1[r];
                        if (s < tv0[r]) { tv1[r] = tv0[r]; tk1[r] = tk0[r]; tv0[r] = s; tk0[r] = k; }
                        else            { tv1[r] = s;      tk1[r] = k; }
                    } else { tv2[r] = s; tk2[r] = k; }
                }
            }
        }
    }

    // ---- cross-lane fp32 rowmin (16 lanes share a row group) ----
    float rowmin[4];
#pragma unroll
    for (int r = 0; r < 4; ++r) {
        float v = tv0[r];
#pragma unroll
        for (int m = 1; m <= 8; m <<= 1) v = fminf(v, __shfl_xor(v, m));
        rowmin[r] = v;
    }

    // ---- fp64 refine of candidates within margin ----
    const float margin = 4e-4f;
    double bestv[4]; int bestk[4];
#pragma unroll
    for (int r = 0; r < 4; ++r) { bestv[r] = 1e300; bestk[r] = 0x7FFFFFFF; }
    for (int r = 0; r < 4; ++r) {
        const int row = r0 + ((l >> 4) << 2) + r;
        const float4* x4 = (const float4*)(x + (size_t)row * DIM);
        float cv[3] = {tv0[r], tv1[r], tv2[r]};
        int   ck[3] = {tk0[r], tk1[r], tk2[r]};
        for (int j = 0; j < 3; ++j) {
            if (cv[j] <= rowmin[r] + margin) {
                const int k = ck[j];
                const float4* w4 = (const float4*)(wT + (size_t)k * DIM);
                double d0 = 0, d1 = 0, d2 = 0, d3 = 0;
#pragma unroll 4
                for (int i = 0; i < 64; ++i) {
                    float4 a = x4[i], b = w4[i];
                    d0 = fma((double)a.x, (double)b.x, d0);
                    d1 = fma((double)a.y, (double)b.y, d1);
                    d2 = fma((double)a.z, (double)b.z, d2);
                    d3 = fma((double)a.w, (double)b.w, d3);
                }
                double s64 = wnorm64[k] - 2.0 * ((d0 + d1) + (d2 + d3));
                if (s64 < bestv[r] || (s64 == bestv[r] && k < bestk[r])) { bestv[r] = s64; bestk[r] = k; }
            }
        }
    }

    // ---- cross-lane fp64 argmin + write indices ----
#pragma unroll
    for (int r = 0; r < 4; ++r) {
        double v = bestv[r]; int k = bestk[r];
#pragma unroll
        for (int m = 1; m <= 8; m <<= 1) {
            double ov = __shfl_xor(v, m); int ok = __shfl_xor(k, m);
            if (ov < v || (ov == v && ok < k)) { v = ov; k = ok; }
        }
        if ((l & 15) == 0) {
            const int rowLocal = wv * 16 + ((l >> 4) << 2) + r;
            rowk[rowLocal] = k;
            out_idx[blockRow0 + rowLocal] = (float)k;
            atomicAdd(&counts[k], 1);
        }
    }
    __syncthreads();

    // ---- epilogue: out_q + one-hot + loss, one row per wave-iteration ----
    double lsum = 0.0;
    for (int rr = 0; rr < 16; ++rr) {
        const int rowLocal = wv * 16 + rr;
        const int row = blockRow0 + rowLocal;
        const int k = rowk[rowLocal];
        float4 xv = ((const float4*)(x  + (size_t)row * DIM))[l];
        float4 qv = ((const float4*)(wT + (size_t)k  * DIM))[l];
        float4 o;
        o.x = xv.x + (qv.x - xv.x); o.y = xv.y + (qv.y - xv.y);
        o.z = xv.z + (qv.z - xv.z); o.w = xv.w + (qv.w - xv.w);
        ((float4*)(out_q + (size_t)row * DIM))[l] = o;
        double dx = (double)qv.x - (double)xv.x; lsum += dx * dx;
        dx = (double)qv.y - (double)xv.y; lsum += dx * dx;
        dx = (double)qv.z - (double)xv.z; lsum += dx * dx;
        dx = (double)qv.w - (double)xv.w; lsum += dx * dx;
        // one-hot row: float2 stores (enc base is only 8B-aligned in d_out)
        float* er = out_enc + (size_t)row * KC;
        float2* er2 = (float2*)er;
        float2 z = {0.f, 0.f};
#pragma unroll
        for (int i = 0; i < 8; ++i) er2[l * 8 + i] = z;
        if (l == (k >> 4)) er[k] = 1.0f;
    }
#pragma unroll
    for (int off = 32; off > 0; off >>= 1) lsum += __shfl_down(lsum, off);
    if (l == 0) wsum[wv] = lsum;
    __syncthreads();
    if (t == 0) atomicAdd(loss_sum, wsum[0] + wsum[1] + wsum[2] + wsum[3]);
}

// ---------- finalize ----------
__global__ __launch_bounds__(1024) void final_kernel(const int* __restrict__ counts,
                                                     const double* __restrict__ loss_sum,
                                                     float* __restrict__ out_loss,
                                                     float* __restrict__ out_ppl) {
    const int t = threadIdx.x;
    double p = (double)counts[t] * (1.0 / 32768.0);
    double term = -p * log(p + 1e-10);
#pragma unroll
    for (int off = 32; off > 0; off >>= 1) term += __shfl_down(term, off);
    __shared__ double ws[16];
    if ((t & 63) == 0) ws[t >> 6] = term;
    __syncthreads();
    if (t == 0) {
        double s = 0.0;
        for (int i = 0; i < 16; ++i) s += ws[i];
        *out_ppl = (float)exp(s);
        *out_loss = (float)(1.25 * loss_sum[0] * (1.0 / 8388608.0));
    }
}

extern "C" void kernel_launch(void* const* d_in, const int* in_sizes, int n_in,
                              void* d_out, int out_size, void* d_ws, size_t ws_size,
                              hipStream_t stream) {
    const float* x = (const float*)d_in[0];   // [32,32,32,256] fp32
    const float* w = (const float*)d_in[1];   // [256,1024] fp32

    float* out = (float*)d_out;
    float* out_q    = out;                        // 8388608
    float* out_loss = out + 8388608;              // 1
    float* out_ppl  = out + 8388609;              // 1
    float* out_enc  = out + 8388610;              // 33554432
    float* out_idx  = out + 8388610 + 33554432;   // 32768

    // ws layout (16B aligned offsets)
    char* wsb = (char*)d_ws;
    double* loss_sum = (double*)(wsb + 0);
    int*    counts   = (int*)(wsb + 64);          // 4096 B
    double* wnorm64  = (double*)(wsb + 4160);     // 8192 B
    float*  wnormf   = (float*)(wsb + 12352);     // 4096 B
    float*  wT       = (float*)(wsb + 16448);     // 1 MB
    uint4*  wph      = (uint4*)(wsb + 1065024);   // 512 KB
    uint4*  wpl      = (uint4*)(wsb + 1589312);   // 512 KB  (end ~2.02 MB)

    hipMemsetAsync(d_ws, 0, 4160, stream);        // loss_sum + counts

    prep_w<<<128, 256, 0, stream>>>(w, wph, wpl, wT);
    wnorm_kernel<<<4, 256, 0, stream>>>(wT, wnorm64, wnormf);
    vq_mfma<<<512, 256, 0, stream>>>(x, (const char*)wph, (const char*)wpl, wT,
                                     wnorm64, wnormf,
                                     out_q, out_idx, out_enc, counts, loss_sum);
    final_kernel<<<1, 1024, 0, stream>>>(counts, loss_sum, out_loss, out_ppl);
}